// Round 4
// baseline (1046.640 us; speedup 1.0000x reference)
//
#include <hip/hip_runtime.h>

#define DEV_INLINE __device__ __forceinline__

typedef short bf16x8 __attribute__((ext_vector_type(8)));
typedef float f32x4 __attribute__((ext_vector_type(4)));

DEV_INLINE float sigmoidf_(float x) { return 1.f / (1.f + __expf(-x)); }
DEV_INLINE float dot4_(float4 a, float4 b) {
    return a.x * b.x + a.y * b.y + a.z * b.z + a.w * b.w;
}
DEV_INLINE unsigned short f2bf(float x) {
    unsigned int u = __float_as_uint(x);
    unsigned int r = (u + 0x7FFFu + ((u >> 16) & 1u)) >> 16;
    return (unsigned short)r;
}
DEV_INLINE float bf2f(unsigned short u) {
    return __uint_as_float(((unsigned int)u) << 16);
}

// ---------------------------------------------------------------------------
// cast fp32 -> bf16 (RNE), vectorized x4, guarded
// ---------------------------------------------------------------------------
__global__ __launch_bounds__(256) void cast_bf16_kernel(
    const float4* __restrict__ in, ushort4* __restrict__ out, int n4)
{
    int i = blockIdx.x * 256 + threadIdx.x;
    if (i >= n4) return;
    float4 v = in[i];
    ushort4 o = {f2bf(v.x), f2bf(v.y), f2bf(v.z), f2bf(v.w)};
    out[i] = o;
}

// ---------------------------------------------------------------------------
// bf16 MFMA GEMM (m97 structure): C[M,N] = act(A[M,K] @ B[N,K]^T + bias)(+res)
// 128x128 tile, BK=32, 4 waves, 4x4 16x16x32 fragments per wave.
// M may be < grid coverage (store guard); N, K must be tile-exact.
// ---------------------------------------------------------------------------
template<int ACT, int RES, int WF32, int WBF>
__global__ __launch_bounds__(256) void mfma_gemm(
    const unsigned short* __restrict__ A, const unsigned short* __restrict__ B,
    const float* __restrict__ bias, const float* __restrict__ res,
    float* __restrict__ C, unsigned short* __restrict__ Cb, int M, int N, int K)
{
    __shared__ __align__(16) unsigned short As[128 * 32];
    __shared__ __align__(16) unsigned short Bs[128 * 32];

    const int t = threadIdx.x;
    const int lane = t & 63, wave = t >> 6;
    const int wr = wave >> 1, wc = wave & 1;
    const int lr = lane & 15, lk = lane >> 4;
    const int m0 = blockIdx.y * 128, n0 = blockIdx.x * 128;

    f32x4 acc[4][4] = {};

    for (int k0 = 0; k0 < K; k0 += 32) {
#pragma unroll
        for (int c = 0; c < 2; c++) {
            int bo = t * 16 + c * 4096;       // byte offset into 8KB tile
            int row = bo >> 6;                // 64 B per row (32 bf16)
            int col = (bo & 63) >> 1;
            __builtin_amdgcn_global_load_lds(
                (const __attribute__((address_space(1))) void*)(A + (size_t)(m0 + row) * K + k0 + col),
                (__attribute__((address_space(3))) void*)(As + (bo >> 1)), 16, 0, 0);
            __builtin_amdgcn_global_load_lds(
                (const __attribute__((address_space(1))) void*)(B + (size_t)(n0 + row) * K + k0 + col),
                (__attribute__((address_space(3))) void*)(Bs + (bo >> 1)), 16, 0, 0);
        }
        __syncthreads();

        bf16x8 af[4], bfr[4];
#pragma unroll
        for (int mi = 0; mi < 4; mi++)
            af[mi] = *(const bf16x8*)(As + (wr * 64 + mi * 16 + lr) * 32 + lk * 8);
#pragma unroll
        for (int nj = 0; nj < 4; nj++)
            bfr[nj] = *(const bf16x8*)(Bs + (wc * 64 + nj * 16 + lr) * 32 + lk * 8);
#pragma unroll
        for (int mi = 0; mi < 4; mi++)
#pragma unroll
            for (int nj = 0; nj < 4; nj++)
                acc[mi][nj] = __builtin_amdgcn_mfma_f32_16x16x32_bf16(
                    af[mi], bfr[nj], acc[mi][nj], 0, 0, 0);
        __syncthreads();
    }

#pragma unroll
    for (int nj = 0; nj < 4; nj++) {
        int col = n0 + wc * 64 + nj * 16 + lr;
        float bv = bias ? bias[col] : 0.f;
#pragma unroll
        for (int mi = 0; mi < 4; mi++) {
            int row = m0 + wr * 64 + mi * 16 + lk * 4;
#pragma unroll
            for (int j = 0; j < 4; j++) {
                int r = row + j;
                if (r >= M) continue;
                float v = acc[mi][nj][j] + bv;
                if (ACT) v = v * sigmoidf_(v - 1.f);
                size_t off = (size_t)r * N + col;
                if (RES) v += res[off];
                if (WF32) C[off] = v;
                if (WBF) Cb[off] = f2bf(v);
            }
        }
    }
}

// ---------------------------------------------------------------------------
// Split qkv (L,N,768) into qu/qv/k/v in (N,H,L,d) layout; qu=q+pos_bias_u etc.
// ---------------------------------------------------------------------------
__global__ __launch_bounds__(256) void split_kernel(
    const float* __restrict__ qkv,
    const float* __restrict__ pbu, const float* __restrict__ pbv,
    float* __restrict__ qu, float* __restrict__ qv,
    float* __restrict__ kb, float* __restrict__ vb)
{
    int idx = blockIdx.x * 256 + threadIdx.x;   // ((n*8+h)*1024 + l)*32 + dd
    int dd = idx & 31;
    int l  = (idx >> 5) & 1023;
    int h  = (idx >> 15) & 7;
    int n  = idx >> 18;
    size_t base = ((size_t)l * 4 + n) * 768 + h * 32 + dd;
    float q = qkv[base];
    qu[idx] = q + pbu[h * 32 + dd];
    qv[idx] = q + pbv[h * 32 + dd];
    kb[idx] = qkv[base + 256];
    vb[idx] = qkv[base + 512];
}

// ---------------------------------------------------------------------------
// Repack p (m,h,d) -> p2 (h,m,d);  m in [0,2047)
// ---------------------------------------------------------------------------
__global__ __launch_bounds__(256) void repack_p_kernel(
    const float* __restrict__ pb, float* __restrict__ p2)
{
    int idx = blockIdx.x * 256 + threadIdx.x;
    if (idx >= 2047 * 256) return;
    int dd = idx & 31;
    int h  = (idx >> 5) & 7;
    int m  = idx >> 8;
    p2[((size_t)h * 2047 + m) * 32 + dd] = pb[idx];
}

// ---------------------------------------------------------------------------
// scores_kernel: totb[n,h,i,j] = bf16((ac + bd) * scale)
// ---------------------------------------------------------------------------
__global__ __launch_bounds__(256) void scores_kernel(
    const float* __restrict__ qu, const float* __restrict__ qv,
    const float* __restrict__ kb, const float* __restrict__ p2,
    unsigned short* __restrict__ totb)
{
    __shared__ float4 Qu4[8][64];
    __shared__ float4 Qv4[8][64];
    __shared__ float4 K4[8][64];
    __shared__ float4 P4[8][128];

    const int t = threadIdx.x;
    const int j0 = blockIdx.x * 64, i0 = blockIdx.y * 64;
    const int nh = blockIdx.z;       // n*8+h
    const int h = nh & 7;
    const int m_base = 960 - i0 + j0;

    const float4* qug = (const float4*)(qu + ((size_t)nh * 1024 + i0) * 32);
    const float4* qvg = (const float4*)(qv + ((size_t)nh * 1024 + i0) * 32);
    const float4* kg  = (const float4*)(kb + ((size_t)nh * 1024 + j0) * 32);
    const float4* pg  = (const float4*)(p2 + ((size_t)h * 2047 + m_base) * 32);

#pragma unroll
    for (int c = 0; c < 2; c++) {
        int fi = t + 256 * c;
        int r = fi >> 3, dg = fi & 7;
        Qu4[dg][r] = qug[fi];
        Qv4[dg][r] = qvg[fi];
        K4[dg][r]  = kg[fi];
    }
#pragma unroll
    for (int c = 0; c < 4; c++) {
        int fi = t + 256 * c;
        if (fi < 127 * 8) {
            int r = fi >> 3, dg = fi & 7;
            P4[dg][r] = pg[fi];
        }
    }
    __syncthreads();

    const int tx = t & 15, ty = t >> 4;
    float acc[4][4] = {};

#pragma unroll
    for (int dg = 0; dg < 8; dg++) {
        float4 a[4], b[4];
#pragma unroll
        for (int ii = 0; ii < 4; ii++) a[ii] = Qu4[dg][ty * 4 + ii];
#pragma unroll
        for (int jj = 0; jj < 4; jj++) b[jj] = K4[dg][tx * 4 + jj];
#pragma unroll
        for (int ii = 0; ii < 4; ii++)
#pragma unroll
            for (int jj = 0; jj < 4; jj++)
                acc[ii][jj] += dot4_(a[ii], b[jj]);
    }

    const int pb_ = 4 * (tx - ty) + 60;
#pragma unroll
    for (int dg = 0; dg < 8; dg++) {
        float4 qvr[4], pr[7];
#pragma unroll
        for (int ii = 0; ii < 4; ii++) qvr[ii] = Qv4[dg][ty * 4 + ii];
#pragma unroll
        for (int s = 0; s < 7; s++) pr[s] = P4[dg][pb_ + s];
#pragma unroll
        for (int ii = 0; ii < 4; ii++)
#pragma unroll
            for (int jj = 0; jj < 4; jj++)
                acc[ii][jj] += dot4_(qvr[ii], pr[jj - ii + 3]);
    }

    const float scale = 0.17677669529663687f;
    unsigned short* o = totb + ((size_t)nh * 1024 + i0) * 1024 + j0;
#pragma unroll
    for (int ii = 0; ii < 4; ii++) {
        ushort4 w = {f2bf(acc[ii][0] * scale), f2bf(acc[ii][1] * scale),
                     f2bf(acc[ii][2] * scale), f2bf(acc[ii][3] * scale)};
        ((ushort4*)(o + (size_t)(ty * 4 + ii) * 1024))[tx] = w;
    }
}

// ---------------------------------------------------------------------------
// attn_finish_kernel: per (n,i):
//   th[h][j] = totb[n,h,i,j] + sum_g as[n,i,j,g]*pin[g,h]
//   out_s[n,i,j,g] = sum_h th[h][j]*po[h,g] + as[n,i,j,g]
//   totb[n,h,i,j] = bf16(softmax_j(th[h][j]))   (in place)
// ---------------------------------------------------------------------------
__global__ __launch_bounds__(256, 4) void attn_finish_kernel(
    unsigned short* __restrict__ totb, const float* __restrict__ as_,
    const float* __restrict__ proj_in, const float* __restrict__ proj_out,
    float* __restrict__ out_s)
{
    __shared__ float row[8 * 1024];
    __shared__ float pin_s[64], po_s[64];
    __shared__ float rs_s[8];

    const int t = threadIdx.x;
    const int n = blockIdx.x >> 10;
    const int i = blockIdx.x & 1023;

    float4* row4 = (float4*)row;

    if (t < 64) { pin_s[t] = proj_in[t]; po_s[t] = proj_out[t]; }
#pragma unroll
    for (int h = 0; h < 8; h++) {
        const ushort4* g2 = (const ushort4*)(totb + ((size_t)(n * 8 + h) * 1024 + i) * 1024);
        ushort4 u = g2[t];
        float4 f = {bf2f(u.x), bf2f(u.y), bf2f(u.z), bf2f(u.w)};
        row4[h * 256 + t] = f;
    }
    __syncthreads();

    const float4* as4 = (const float4*)(as_ + ((size_t)(n * 1024 + i) * 1024) * 8);
    float4* os4 = (float4*)(out_s + ((size_t)(n * 1024 + i) * 1024) * 8);
#pragma unroll
    for (int c = 0; c < 4; c++) {
        int j = t + 256 * c;
        float4 alo = as4[j * 2], ahi = as4[j * 2 + 1];
        float ag[8] = {alo.x, alo.y, alo.z, alo.w, ahi.x, ahi.y, ahi.z, ahi.w};
        float th[8];
#pragma unroll
        for (int h = 0; h < 8; h++) {
            float si = 0.f;
#pragma unroll
            for (int g = 0; g < 8; g++) si += ag[g] * pin_s[g * 8 + h];
            th[h] = row[h * 1024 + j] + si;
            row[h * 1024 + j] = th[h];
        }
        float so[8];
#pragma unroll
        for (int g = 0; g < 8; g++) {
            float s = ag[g];
#pragma unroll
            for (int h = 0; h < 8; h++) s += th[h] * po_s[h * 8 + g];
            so[g] = s;
        }
        float4 o0 = {so[0], so[1], so[2], so[3]};
        float4 o1 = {so[4], so[5], so[6], so[7]};
        os4[j * 2] = o0;
        os4[j * 2 + 1] = o1;
    }
    __syncthreads();

    {
        const int h = t >> 5, s = t & 31;
        float* r = row + h * 1024;
        float mx = -1e30f;
#pragma unroll 8
        for (int e = 0; e < 32; e++) mx = fmaxf(mx, r[e * 32 + s]);
#pragma unroll
        for (int d = 1; d < 32; d <<= 1) mx = fmaxf(mx, __shfl_xor(mx, d));
        float sm = 0.f;
#pragma unroll 8
        for (int e = 0; e < 32; e++) {
            float v = __expf(r[e * 32 + s] - mx);
            r[e * 32 + s] = v;
            sm += v;
        }
#pragma unroll
        for (int d = 1; d < 32; d <<= 1) sm += __shfl_xor(sm, d);
        if (s == 0) rs_s[h] = 1.f / sm;
    }
    __syncthreads();

#pragma unroll
    for (int h = 0; h < 8; h++) {
        float rs = rs_s[h];
        float4 v = row4[h * 256 + t];
        ushort4 o = {f2bf(v.x * rs), f2bf(v.y * rs), f2bf(v.z * rs), f2bf(v.w * rs)};
        ((ushort4*)(totb + ((size_t)(n * 8 + h) * 1024 + i) * 1024))[t] = o;
    }
}

// ---------------------------------------------------------------------------
// ctx_kernel: ctx[i, n, h*32+d] = sum_j attn_bf16[i,j]*v[j,d]  (bf16 output)
// ---------------------------------------------------------------------------
__global__ __launch_bounds__(256) void ctx_kernel(
    const unsigned short* __restrict__ attnb, const float* __restrict__ vb,
    unsigned short* __restrict__ ctx_b)
{
    __shared__ float At[64][128];
    __shared__ float Vs[128][32];

    const int t = threadIdx.x;
    const int i0 = blockIdx.x * 64;
    const int nh = blockIdx.y;           // n*8+h
    const int n = nh >> 3, h = nh & 7;
    const int tx = t & 31, ty = t >> 5;

    float acc[8] = {};
    const unsigned short* abase = attnb + ((size_t)nh * 1024 + i0) * 1024;
    const float* vbase = vb + (size_t)nh * 1024 * 32;

    for (int jc = 0; jc < 8; jc++) {
#pragma unroll
        for (int c = 0; c < 8; c++) {
            int fi = t + 256 * c;             // 2048 ushort4
            int r = fi >> 5, c4 = fi & 31;
            ushort4 u = ((const ushort4*)(abase + (size_t)r * 1024 + jc * 128))[c4];
            float4 f = {bf2f(u.x), bf2f(u.y), bf2f(u.z), bf2f(u.w)};
            ((float4*)At[r])[c4] = f;
        }
#pragma unroll
        for (int c = 0; c < 4; c++) {
            int fi = t + 256 * c;
            int r = fi >> 3, dg = fi & 7;
            ((float4*)Vs[r])[dg] =
                ((const float4*)(vbase + (size_t)(jc * 128 + r) * 32))[dg];
        }
        __syncthreads();
#pragma unroll
        for (int jj = 0; jj < 32; jj++) {
            float v0 = Vs[jj * 4 + 0][tx];
            float v1 = Vs[jj * 4 + 1][tx];
            float v2 = Vs[jj * 4 + 2][tx];
            float v3 = Vs[jj * 4 + 3][tx];
#pragma unroll
            for (int ii = 0; ii < 8; ii++) {
                float4 av = ((float4*)At[ty * 8 + ii])[jj];
                acc[ii] += av.x * v0 + av.y * v1 + av.z * v2 + av.w * v3;
            }
        }
        __syncthreads();
    }

#pragma unroll
    for (int ii = 0; ii < 8; ii++) {
        int i = i0 + ty * 8 + ii;
        ctx_b[((size_t)i * 4 + n) * 256 + h * 32 + tx] = f2bf(acc[ii]);
    }
}

// ---------------------------------------------------------------------------
// GLU
// ---------------------------------------------------------------------------
__global__ __launch_bounds__(256) void glu_kernel(
    const float* __restrict__ h1, float* __restrict__ g)
{
    int idx = blockIdx.x * 256 + threadIdx.x;
    int r = idx >> 9, c = idx & 511;
    float a = h1[(size_t)r * 1024 + c];
    float b = h1[(size_t)r * 1024 + 512 + c];
    g[idx] = a * sigmoidf_(b);
}

// ---------------------------------------------------------------------------
// depthwise conv (K=31, pad 15) + bias + DoubleSwish -> bf16
// ---------------------------------------------------------------------------
__global__ __launch_bounds__(256) void dwconv_kernel(
    const float* __restrict__ g, const float* __restrict__ w_dw,
    const float* __restrict__ b_dw, unsigned short* __restrict__ out)
{
    int idx = blockIdx.x * 256 + threadIdx.x;
    int c = idx & 511;
    int r = idx >> 9;
    int nn = r & 3, l = r >> 2;
    float acc = b_dw[c];
#pragma unroll
    for (int kk = 0; kk < 31; kk++) {
        int l2 = l + kk - 15;
        if (l2 >= 0 && l2 < 1024)
            acc += g[(((size_t)l2 * 4 + nn) << 9) + c] * w_dw[c * 31 + kk];
    }
    out[idx] = f2bf(acc * sigmoidf_(acc - 1.f));
}

// ---------------------------------------------------------------------------
// BasicNorm
// ---------------------------------------------------------------------------
__global__ __launch_bounds__(256) void norm_kernel(
    const float* __restrict__ x, const float* __restrict__ eps_p,
    float* __restrict__ out)
{
    int r = blockIdx.x, t = threadIdx.x;
    float a = x[(size_t)r * 512 + t];
    float b = x[(size_t)r * 512 + 256 + t];
    float ss = a * a + b * b;
#pragma unroll
    for (int d = 1; d < 64; d <<= 1) ss += __shfl_xor(ss, d);
    __shared__ float red[4];
    if ((t & 63) == 0) red[t >> 6] = ss;
    __syncthreads();
    float tot = red[0] + red[1] + red[2] + red[3];
    float scale = rsqrtf(tot * (1.f / 512.f) + __expf(eps_p[0]));
    out[(size_t)r * 512 + t] = a * scale;
    out[(size_t)r * 512 + 256 + t] = b * scale;
}

// ---------------------------------------------------------------------------
extern "C" void kernel_launch(void* const* d_in, const int* in_sizes, int n_in,
                              void* d_out, int out_size, void* d_ws, size_t ws_size,
                              hipStream_t stream)
{
    const float* src   = (const float*)d_in[0];
    const float* pos   = (const float*)d_in[1];
    const float* as_   = (const float*)d_in[2];
    const float* w_in  = (const float*)d_in[3];
    const float* b_in  = (const float*)d_in[4];
    const float* w_pos = (const float*)d_in[5];
    const float* pbu   = (const float*)d_in[6];
    const float* pbv   = (const float*)d_in[7];
    const float* prin  = (const float*)d_in[8];
    const float* prout = (const float*)d_in[9];
    const float* w_out = (const float*)d_in[10];
    const float* b_out = (const float*)d_in[11];
    const float* w_ff1m = (const float*)d_in[12];
    const float* b_ff1m = (const float*)d_in[13];
    const float* w_ff2m = (const float*)d_in[14];
    const float* b_ff2m = (const float*)d_in[15];
    const float* w_ff1 = (const float*)d_in[16];
    const float* b_ff1 = (const float*)d_in[17];
    const float* w_ff2 = (const float*)d_in[18];
    const float* b_ff2 = (const float*)d_in[19];
    const float* w_pw1 = (const float*)d_in[20];
    const float* b_pw1 = (const float*)d_in[21];
    const float* w_dw  = (const float*)d_in[22];
    const float* b_dw  = (const float*)d_in[23];
    const float* w_pw2 = (const float*)d_in[24];
    const float* b_pw2 = (const float*)d_in[25];
    const float* neps  = (const float*)d_in[26];

    float* out_x = (float*)d_out;                       // 4096*512
    float* out_s = (float*)d_out + 2097152;             // 4*1024*1024*8

    // ---- workspace layout (float units) ----
    float* ws = (float*)d_ws;
    float* xbuf = ws;                               // 2,097,152
    float* U    = xbuf + 2097152;                   // 6,291,456 (hb16 | hbuf+gbuf)
    float* sbbf = U + 6291456;                      // 1,048,576 (src bf16 | dbufb)
    float* xb16f= sbbf + 1048576;                   // 1,048,576
    float* qkvb = xb16f + 1048576;                  // 3,145,728 (later p2)
    float* qu   = qkvb + 3145728;                   // 1,048,576 (later ctxb)
    float* qv   = qu + 1048576;                     // 1,048,576
    float* kbuf = qv + 1048576;                     // 1,048,576
    float* vbuf = kbuf + 1048576;                   // 1,048,576
    float* pbuf = vbuf + 1048576;                   // 524,288
    float* wbf  = pbuf + 524288;                    // 524,288 (weight bf16 staging)
    float* posbf= wbf + 524288;                     // 524,288 (pos bf16, 2048x512)
    float* totf = posbf + 524288;                   // 16,777,216 (bf16 tot, 33.5M elems)

    unsigned short* hb16  = (unsigned short*)U;           // 8,388,608 elems
    float*          hbuf  = U;                            // pw1 out (4096x1024)
    float*          gbuf  = U + 4194304;                  // GLU out (4096x512)
    unsigned short* sbb   = (unsigned short*)sbbf;        // src bf16
    unsigned short* dbufb = (unsigned short*)sbbf;        // dwconv out bf16
    unsigned short* xb16  = (unsigned short*)xb16f;       // x bf16
    unsigned short* ctxb  = (unsigned short*)qu;          // ctx bf16
    unsigned short* wb    = (unsigned short*)wbf;         // weight staging
    unsigned short* posb  = (unsigned short*)posbf;       // pos bf16 padded
    unsigned short* totb  = (unsigned short*)totf;        // scores/attn bf16
    float*          p2    = qkvb;

    dim3 blk(256);
    const int M = 4096;

    // --- macaron FFN ---
    cast_bf16_kernel<<<2048, blk, 0, stream>>>((const float4*)src, (ushort4*)sbb, 524288);
    cast_bf16_kernel<<<1024, blk, 0, stream>>>((const float4*)w_ff1m, (ushort4*)wb, 262144);
    mfma_gemm<1,0,0,1><<<dim3(16, 32), blk, 0, stream>>>(
        sbb, wb, b_ff1m, nullptr, nullptr, hb16, M, 2048, 512);
    cast_bf16_kernel<<<1024, blk, 0, stream>>>((const float4*)w_ff2m, (ushort4*)wb, 262144);
    mfma_gemm<0,1,1,1><<<dim3(4, 32), blk, 0, stream>>>(
        hb16, wb, b_ff2m, src, xbuf, xb16, M, 512, 2048);

    // --- attention ---
    cast_bf16_kernel<<<384, blk, 0, stream>>>((const float4*)w_in, (ushort4*)wb, 98304);
    mfma_gemm<0,0,1,0><<<dim3(6, 32), blk, 0, stream>>>(
        xb16, wb, b_in, nullptr, qkvb, nullptr, M, 768, 512);
    split_kernel<<<4096, blk, 0, stream>>>(qkvb, pbu, pbv, qu, qv, kbuf, vbuf);
    // pos projection via MFMA (M=2047 padded to 2048)
    cast_bf16_kernel<<<1024, blk, 0, stream>>>((const float4*)pos, (ushort4*)posb, 262016);
    cast_bf16_kernel<<<128, blk, 0, stream>>>((const float4*)w_pos, (ushort4*)wb, 32768);
    mfma_gemm<0,0,1,0><<<dim3(2, 16), blk, 0, stream>>>(
        posb, wb, nullptr, nullptr, pbuf, nullptr, 2047, 256, 512);
    repack_p_kernel<<<2047, blk, 0, stream>>>(pbuf, p2);
    scores_kernel<<<dim3(16, 16, 32), blk, 0, stream>>>(qu, qv, kbuf, p2, totb);
    attn_finish_kernel<<<4096, blk, 0, stream>>>(totb, as_, prin, prout, out_s);
    ctx_kernel<<<dim3(16, 32), blk, 0, stream>>>(totb, vbuf, ctxb);
    cast_bf16_kernel<<<128, blk, 0, stream>>>((const float4*)w_out, (ushort4*)wb, 32768);
    mfma_gemm<0,1,1,1><<<dim3(4, 32), blk, 0, stream>>>(
        ctxb, wb, b_out, xbuf, xbuf, xb16, M, 512, 256);

    // --- conv module ---
    cast_bf16_kernel<<<512, blk, 0, stream>>>((const float4*)w_pw1, (ushort4*)wb, 131072);
    mfma_gemm<0,0,1,0><<<dim3(8, 32), blk, 0, stream>>>(
        xb16, wb, b_pw1, nullptr, hbuf, nullptr, M, 1024, 512);
    glu_kernel<<<8192, blk, 0, stream>>>(hbuf, gbuf);
    dwconv_kernel<<<8192, blk, 0, stream>>>(gbuf, w_dw, b_dw, dbufb);
    cast_bf16_kernel<<<256, blk, 0, stream>>>((const float4*)w_pw2, (ushort4*)wb, 65536);
    mfma_gemm<0,1,1,1><<<dim3(4, 32), blk, 0, stream>>>(
        dbufb, wb, b_pw2, xbuf, xbuf, xb16, M, 512, 512);

    // --- final FFN + BasicNorm ---
    cast_bf16_kernel<<<1024, blk, 0, stream>>>((const float4*)w_ff1, (ushort4*)wb, 262144);
    mfma_gemm<1,0,0,1><<<dim3(16, 32), blk, 0, stream>>>(
        xb16, wb, b_ff1, nullptr, nullptr, hb16, M, 2048, 512);
    cast_bf16_kernel<<<1024, blk, 0, stream>>>((const float4*)w_ff2, (ushort4*)wb, 262144);
    mfma_gemm<0,1,1,0><<<dim3(4, 32), blk, 0, stream>>>(
        hb16, wb, b_ff2, xbuf, xbuf, nullptr, M, 512, 2048);
    norm_kernel<<<4096, blk, 0, stream>>>(xbuf, neps, out_x);
}

// Round 5
// 759.620 us; speedup vs baseline: 1.3778x; 1.3778x over previous
//
#include <hip/hip_runtime.h>

#define DEV_INLINE __device__ __forceinline__

typedef short bf16x8 __attribute__((ext_vector_type(8)));
typedef float f32x4 __attribute__((ext_vector_type(4)));

DEV_INLINE float sigmoidf_(float x) { return 1.f / (1.f + __expf(-x)); }
DEV_INLINE float dot4_(float4 a, float4 b) {
    return a.x * b.x + a.y * b.y + a.z * b.z + a.w * b.w;
}
DEV_INLINE unsigned short f2bf(float x) {
    unsigned int u = __float_as_uint(x);
    unsigned int r = (u + 0x7FFFu + ((u >> 16) & 1u)) >> 16;
    return (unsigned short)r;
}
DEV_INLINE float bf2f(unsigned short u) {
    return __uint_as_float(((unsigned int)u) << 16);
}

// ---------------------------------------------------------------------------
// cast fp32 -> bf16 (RNE), vectorized x4, guarded
// ---------------------------------------------------------------------------
__global__ __launch_bounds__(256) void cast_bf16_kernel(
    const float4* __restrict__ in, ushort4* __restrict__ out, int n4)
{
    int i = blockIdx.x * 256 + threadIdx.x;
    if (i >= n4) return;
    float4 v = in[i];
    ushort4 o = {f2bf(v.x), f2bf(v.y), f2bf(v.z), f2bf(v.w)};
    out[i] = o;
}

// ---------------------------------------------------------------------------
// bf16 MFMA GEMM (m97 structure): C[M,N] = act(A[M,K] @ B[N,K]^T + bias)(+res)
// 128x128 tile, BK=32, 4 waves, 4x4 16x16x32 fragments per wave.
// M may be < grid coverage (store guard); N, K must be tile-exact.
// ---------------------------------------------------------------------------
template<int ACT, int RES, int WF32, int WBF>
__global__ __launch_bounds__(256) void mfma_gemm(
    const unsigned short* __restrict__ A, const unsigned short* __restrict__ B,
    const float* __restrict__ bias, const float* __restrict__ res,
    float* __restrict__ C, unsigned short* __restrict__ Cb, int M, int N, int K)
{
    __shared__ __align__(16) unsigned short As[128 * 32];
    __shared__ __align__(16) unsigned short Bs[128 * 32];

    const int t = threadIdx.x;
    const int lane = t & 63, wave = t >> 6;
    const int wr = wave >> 1, wc = wave & 1;
    const int lr = lane & 15, lk = lane >> 4;
    const int m0 = blockIdx.y * 128, n0 = blockIdx.x * 128;

    f32x4 acc[4][4] = {};

    for (int k0 = 0; k0 < K; k0 += 32) {
#pragma unroll
        for (int c = 0; c < 2; c++) {
            int bo = t * 16 + c * 4096;       // byte offset into 8KB tile
            int row = bo >> 6;                // 64 B per row (32 bf16)
            int col = (bo & 63) >> 1;
            __builtin_amdgcn_global_load_lds(
                (const __attribute__((address_space(1))) void*)(A + (size_t)(m0 + row) * K + k0 + col),
                (__attribute__((address_space(3))) void*)(As + (bo >> 1)), 16, 0, 0);
            __builtin_amdgcn_global_load_lds(
                (const __attribute__((address_space(1))) void*)(B + (size_t)(n0 + row) * K + k0 + col),
                (__attribute__((address_space(3))) void*)(Bs + (bo >> 1)), 16, 0, 0);
        }
        __syncthreads();

        bf16x8 af[4], bfr[4];
#pragma unroll
        for (int mi = 0; mi < 4; mi++)
            af[mi] = *(const bf16x8*)(As + (wr * 64 + mi * 16 + lr) * 32 + lk * 8);
#pragma unroll
        for (int nj = 0; nj < 4; nj++)
            bfr[nj] = *(const bf16x8*)(Bs + (wc * 64 + nj * 16 + lr) * 32 + lk * 8);
#pragma unroll
        for (int mi = 0; mi < 4; mi++)
#pragma unroll
            for (int nj = 0; nj < 4; nj++)
                acc[mi][nj] = __builtin_amdgcn_mfma_f32_16x16x32_bf16(
                    af[mi], bfr[nj], acc[mi][nj], 0, 0, 0);
        __syncthreads();
    }

#pragma unroll
    for (int nj = 0; nj < 4; nj++) {
        int col = n0 + wc * 64 + nj * 16 + lr;
        float bv = bias ? bias[col] : 0.f;
#pragma unroll
        for (int mi = 0; mi < 4; mi++) {
            int row = m0 + wr * 64 + mi * 16 + lk * 4;
#pragma unroll
            for (int j = 0; j < 4; j++) {
                int r = row + j;
                if (r >= M) continue;
                float v = acc[mi][nj][j] + bv;
                if (ACT) v = v * sigmoidf_(v - 1.f);
                size_t off = (size_t)r * N + col;
                if (RES) v += res[off];
                if (WF32) C[off] = v;
                if (WBF) Cb[off] = f2bf(v);
            }
        }
    }
}

// ---------------------------------------------------------------------------
// Split qkv (L,N,768) into qu/qv/k/v in (N,H,L,d) layout; qu=q+pos_bias_u etc.
// ---------------------------------------------------------------------------
__global__ __launch_bounds__(256) void split_kernel(
    const float* __restrict__ qkv,
    const float* __restrict__ pbu, const float* __restrict__ pbv,
    float* __restrict__ qu, float* __restrict__ qv,
    float* __restrict__ kb, float* __restrict__ vb)
{
    int idx = blockIdx.x * 256 + threadIdx.x;   // ((n*8+h)*1024 + l)*32 + dd
    int dd = idx & 31;
    int l  = (idx >> 5) & 1023;
    int h  = (idx >> 15) & 7;
    int n  = idx >> 18;
    size_t base = ((size_t)l * 4 + n) * 768 + h * 32 + dd;
    float q = qkv[base];
    qu[idx] = q + pbu[h * 32 + dd];
    qv[idx] = q + pbv[h * 32 + dd];
    kb[idx] = qkv[base + 256];
    vb[idx] = qkv[base + 512];
}

// ---------------------------------------------------------------------------
// Repack p (m,h,d) -> p2 (h,m,d);  m in [0,2047)
// ---------------------------------------------------------------------------
__global__ __launch_bounds__(256) void repack_p_kernel(
    const float* __restrict__ pb, float* __restrict__ p2)
{
    int idx = blockIdx.x * 256 + threadIdx.x;
    if (idx >= 2047 * 256) return;
    int dd = idx & 31;
    int h  = (idx >> 5) & 7;
    int m  = idx >> 8;
    p2[((size_t)h * 2047 + m) * 32 + dd] = pb[idx];
}

// ---------------------------------------------------------------------------
// scores_kernel: totb[n,h,i,j] = bf16((ac + bd) * scale)
// ---------------------------------------------------------------------------
__global__ __launch_bounds__(256) void scores_kernel(
    const float* __restrict__ qu, const float* __restrict__ qv,
    const float* __restrict__ kb, const float* __restrict__ p2,
    unsigned short* __restrict__ totb)
{
    __shared__ float4 Qu4[8][64];
    __shared__ float4 Qv4[8][64];
    __shared__ float4 K4[8][64];
    __shared__ float4 P4[8][128];

    const int t = threadIdx.x;
    const int j0 = blockIdx.x * 64, i0 = blockIdx.y * 64;
    const int nh = blockIdx.z;       // n*8+h
    const int h = nh & 7;
    const int m_base = 960 - i0 + j0;

    const float4* qug = (const float4*)(qu + ((size_t)nh * 1024 + i0) * 32);
    const float4* qvg = (const float4*)(qv + ((size_t)nh * 1024 + i0) * 32);
    const float4* kg  = (const float4*)(kb + ((size_t)nh * 1024 + j0) * 32);
    const float4* pg  = (const float4*)(p2 + ((size_t)h * 2047 + m_base) * 32);

#pragma unroll
    for (int c = 0; c < 2; c++) {
        int fi = t + 256 * c;
        int r = fi >> 3, dg = fi & 7;
        Qu4[dg][r] = qug[fi];
        Qv4[dg][r] = qvg[fi];
        K4[dg][r]  = kg[fi];
    }
#pragma unroll
    for (int c = 0; c < 4; c++) {
        int fi = t + 256 * c;
        if (fi < 127 * 8) {
            int r = fi >> 3, dg = fi & 7;
            P4[dg][r] = pg[fi];
        }
    }
    __syncthreads();

    const int tx = t & 15, ty = t >> 4;
    float acc[4][4] = {};

#pragma unroll
    for (int dg = 0; dg < 8; dg++) {
        float4 a[4], b[4];
#pragma unroll
        for (int ii = 0; ii < 4; ii++) a[ii] = Qu4[dg][ty * 4 + ii];
#pragma unroll
        for (int jj = 0; jj < 4; jj++) b[jj] = K4[dg][tx * 4 + jj];
#pragma unroll
        for (int ii = 0; ii < 4; ii++)
#pragma unroll
            for (int jj = 0; jj < 4; jj++)
                acc[ii][jj] += dot4_(a[ii], b[jj]);
    }

    const int pb_ = 4 * (tx - ty) + 60;
#pragma unroll
    for (int dg = 0; dg < 8; dg++) {
        float4 qvr[4], pr[7];
#pragma unroll
        for (int ii = 0; ii < 4; ii++) qvr[ii] = Qv4[dg][ty * 4 + ii];
#pragma unroll
        for (int s = 0; s < 7; s++) pr[s] = P4[dg][pb_ + s];
#pragma unroll
        for (int ii = 0; ii < 4; ii++)
#pragma unroll
            for (int jj = 0; jj < 4; jj++)
                acc[ii][jj] += dot4_(qvr[ii], pr[jj - ii + 3]);
    }

    const float scale = 0.17677669529663687f;
    unsigned short* o = totb + ((size_t)nh * 1024 + i0) * 1024 + j0;
#pragma unroll
    for (int ii = 0; ii < 4; ii++) {
        ushort4 w = {f2bf(acc[ii][0] * scale), f2bf(acc[ii][1] * scale),
                     f2bf(acc[ii][2] * scale), f2bf(acc[ii][3] * scale)};
        ((ushort4*)(o + (size_t)(ty * 4 + ii) * 1024))[tx] = w;
    }
}

// ---------------------------------------------------------------------------
// attn_finish_kernel (register-resident): per (n,i), thread t owns j=4t..4t+3.
//   th[h][jj] = totb[n,h,i,j] + sum_g as[n,i,j,g]*pin[g,h]   (VGPRs)
//   out_s[n,i,j,g] = sum_h th*po[h,g] + as[n,i,j,g]
//   totb[n,h,i,j] = bf16(softmax_j(th))   (in place)
// ---------------------------------------------------------------------------
__global__ __launch_bounds__(256) void attn_finish_kernel(
    unsigned short* __restrict__ totb, const float* __restrict__ as_,
    const float* __restrict__ proj_in, const float* __restrict__ proj_out,
    float* __restrict__ out_s)
{
    __shared__ float pin_s[64], po_s[64];
    __shared__ float redbuf[4][8];

    const int t = threadIdx.x;
    const int n = blockIdx.x >> 10;
    const int i = blockIdx.x & 1023;
    const int j0 = t * 4;
    const int wave = t >> 6, lane = t & 63;

    if (t < 64) { pin_s[t] = proj_in[t]; po_s[t] = proj_out[t]; }
    __syncthreads();

    // load raw scores into registers (per-thread contiguous 8B per head)
    float th[8][4];
#pragma unroll
    for (int h = 0; h < 8; h++) {
        ushort4 u = *(const ushort4*)(totb + ((size_t)(n * 8 + h) * 1024 + i) * 1024 + j0);
        th[h][0] = bf2f(u.x); th[h][1] = bf2f(u.y);
        th[h][2] = bf2f(u.z); th[h][3] = bf2f(u.w);
    }

    const float4* as4 = (const float4*)(as_ + (((size_t)n * 1024 + i) * 1024 + j0) * 8);
    float4* os4 = (float4*)(out_s + (((size_t)n * 1024 + i) * 1024 + j0) * 8);

#pragma unroll
    for (int jj = 0; jj < 4; jj++) {
        float4 alo = as4[jj * 2], ahi = as4[jj * 2 + 1];
        float ag[8] = {alo.x, alo.y, alo.z, alo.w, ahi.x, ahi.y, ahi.z, ahi.w};
#pragma unroll
        for (int h = 0; h < 8; h++) {
            float si = 0.f;
#pragma unroll
            for (int g = 0; g < 8; g++) si += ag[g] * pin_s[g * 8 + h];
            th[h][jj] += si;
        }
        float so[8];
#pragma unroll
        for (int g = 0; g < 8; g++) {
            float s = ag[g];
#pragma unroll
            for (int h = 0; h < 8; h++) s += th[h][jj] * po_s[h * 8 + g];
            so[g] = s;
        }
        float4 o0 = {so[0], so[1], so[2], so[3]};
        float4 o1 = {so[4], so[5], so[6], so[7]};
        os4[jj * 2] = o0;
        os4[jj * 2 + 1] = o1;
    }

    // --- softmax over j (block-wide reduce of 8 per-head scalars) ---
    float mx[8];
#pragma unroll
    for (int h = 0; h < 8; h++)
        mx[h] = fmaxf(fmaxf(th[h][0], th[h][1]), fmaxf(th[h][2], th[h][3]));
#pragma unroll
    for (int d = 1; d < 64; d <<= 1)
#pragma unroll
        for (int h = 0; h < 8; h++) mx[h] = fmaxf(mx[h], __shfl_xor(mx[h], d));
    if (lane == 0)
#pragma unroll
        for (int h = 0; h < 8; h++) redbuf[wave][h] = mx[h];
    __syncthreads();
#pragma unroll
    for (int h = 0; h < 8; h++)
        mx[h] = fmaxf(fmaxf(redbuf[0][h], redbuf[1][h]),
                      fmaxf(redbuf[2][h], redbuf[3][h]));
    __syncthreads();

    float sm[8];
#pragma unroll
    for (int h = 0; h < 8; h++) {
        float s = 0.f;
#pragma unroll
        for (int jj = 0; jj < 4; jj++) {
            th[h][jj] = __expf(th[h][jj] - mx[h]);
            s += th[h][jj];
        }
        sm[h] = s;
    }
#pragma unroll
    for (int d = 1; d < 64; d <<= 1)
#pragma unroll
        for (int h = 0; h < 8; h++) sm[h] += __shfl_xor(sm[h], d);
    if (lane == 0)
#pragma unroll
        for (int h = 0; h < 8; h++) redbuf[wave][h] = sm[h];
    __syncthreads();

#pragma unroll
    for (int h = 0; h < 8; h++) {
        float rs = 1.f / (redbuf[0][h] + redbuf[1][h] + redbuf[2][h] + redbuf[3][h]);
        ushort4 o = {f2bf(th[h][0] * rs), f2bf(th[h][1] * rs),
                     f2bf(th[h][2] * rs), f2bf(th[h][3] * rs)};
        *(ushort4*)(totb + ((size_t)(n * 8 + h) * 1024 + i) * 1024 + j0) = o;
    }
}

// ---------------------------------------------------------------------------
// ctx_kernel: ctx[i, n, h*32+d] = sum_j attn_bf16[i,j]*v[j,d]  (bf16 output)
// ---------------------------------------------------------------------------
__global__ __launch_bounds__(256) void ctx_kernel(
    const unsigned short* __restrict__ attnb, const float* __restrict__ vb,
    unsigned short* __restrict__ ctx_b)
{
    __shared__ float At[64][128];
    __shared__ float Vs[128][32];

    const int t = threadIdx.x;
    const int i0 = blockIdx.x * 64;
    const int nh = blockIdx.y;           // n*8+h
    const int n = nh >> 3, h = nh & 7;
    const int tx = t & 31, ty = t >> 5;

    float acc[8] = {};
    const unsigned short* abase = attnb + ((size_t)nh * 1024 + i0) * 1024;
    const float* vbase = vb + (size_t)nh * 1024 * 32;

    for (int jc = 0; jc < 8; jc++) {
#pragma unroll
        for (int c = 0; c < 8; c++) {
            int fi = t + 256 * c;             // 2048 ushort4
            int r = fi >> 5, c4 = fi & 31;
            ushort4 u = ((const ushort4*)(abase + (size_t)r * 1024 + jc * 128))[c4];
            float4 f = {bf2f(u.x), bf2f(u.y), bf2f(u.z), bf2f(u.w)};
            ((float4*)At[r])[c4] = f;
        }
#pragma unroll
        for (int c = 0; c < 4; c++) {
            int fi = t + 256 * c;
            int r = fi >> 3, dg = fi & 7;
            ((float4*)Vs[r])[dg] =
                ((const float4*)(vbase + (size_t)(jc * 128 + r) * 32))[dg];
        }
        __syncthreads();
#pragma unroll
        for (int jj = 0; jj < 32; jj++) {
            float v0 = Vs[jj * 4 + 0][tx];
            float v1 = Vs[jj * 4 + 1][tx];
            float v2 = Vs[jj * 4 + 2][tx];
            float v3 = Vs[jj * 4 + 3][tx];
#pragma unroll
            for (int ii = 0; ii < 8; ii++) {
                float4 av = ((float4*)At[ty * 8 + ii])[jj];
                acc[ii] += av.x * v0 + av.y * v1 + av.z * v2 + av.w * v3;
            }
        }
        __syncthreads();
    }

#pragma unroll
    for (int ii = 0; ii < 8; ii++) {
        int i = i0 + ty * 8 + ii;
        ctx_b[((size_t)i * 4 + n) * 256 + h * 32 + tx] = f2bf(acc[ii]);
    }
}

// ---------------------------------------------------------------------------
// GLU
// ---------------------------------------------------------------------------
__global__ __launch_bounds__(256) void glu_kernel(
    const float* __restrict__ h1, float* __restrict__ g)
{
    int idx = blockIdx.x * 256 + threadIdx.x;
    int r = idx >> 9, c = idx & 511;
    float a = h1[(size_t)r * 1024 + c];
    float b = h1[(size_t)r * 1024 + 512 + c];
    g[idx] = a * sigmoidf_(b);
}

// ---------------------------------------------------------------------------
// depthwise conv (K=31, pad 15) + bias + DoubleSwish -> bf16
// ---------------------------------------------------------------------------
__global__ __launch_bounds__(256) void dwconv_kernel(
    const float* __restrict__ g, const float* __restrict__ w_dw,
    const float* __restrict__ b_dw, unsigned short* __restrict__ out)
{
    int idx = blockIdx.x * 256 + threadIdx.x;
    int c = idx & 511;
    int r = idx >> 9;
    int nn = r & 3, l = r >> 2;
    float acc = b_dw[c];
#pragma unroll
    for (int kk = 0; kk < 31; kk++) {
        int l2 = l + kk - 15;
        if (l2 >= 0 && l2 < 1024)
            acc += g[(((size_t)l2 * 4 + nn) << 9) + c] * w_dw[c * 31 + kk];
    }
    out[idx] = f2bf(acc * sigmoidf_(acc - 1.f));
}

// ---------------------------------------------------------------------------
// BasicNorm
// ---------------------------------------------------------------------------
__global__ __launch_bounds__(256) void norm_kernel(
    const float* __restrict__ x, const float* __restrict__ eps_p,
    float* __restrict__ out)
{
    int r = blockIdx.x, t = threadIdx.x;
    float a = x[(size_t)r * 512 + t];
    float b = x[(size_t)r * 512 + 256 + t];
    float ss = a * a + b * b;
#pragma unroll
    for (int d = 1; d < 64; d <<= 1) ss += __shfl_xor(ss, d);
    __shared__ float red[4];
    if ((t & 63) == 0) red[t >> 6] = ss;
    __syncthreads();
    float tot = red[0] + red[1] + red[2] + red[3];
    float scale = rsqrtf(tot * (1.f / 512.f) + __expf(eps_p[0]));
    out[(size_t)r * 512 + t] = a * scale;
    out[(size_t)r * 512 + 256 + t] = b * scale;
}

// ---------------------------------------------------------------------------
extern "C" void kernel_launch(void* const* d_in, const int* in_sizes, int n_in,
                              void* d_out, int out_size, void* d_ws, size_t ws_size,
                              hipStream_t stream)
{
    const float* src   = (const float*)d_in[0];
    const float* pos   = (const float*)d_in[1];
    const float* as_   = (const float*)d_in[2];
    const float* w_in  = (const float*)d_in[3];
    const float* b_in  = (const float*)d_in[4];
    const float* w_pos = (const float*)d_in[5];
    const float* pbu   = (const float*)d_in[6];
    const float* pbv   = (const float*)d_in[7];
    const float* prin  = (const float*)d_in[8];
    const float* prout = (const float*)d_in[9];
    const float* w_out = (const float*)d_in[10];
    const float* b_out = (const float*)d_in[11];
    const float* w_ff1m = (const float*)d_in[12];
    const float* b_ff1m = (const float*)d_in[13];
    const float* w_ff2m = (const float*)d_in[14];
    const float* b_ff2m = (const float*)d_in[15];
    const float* w_ff1 = (const float*)d_in[16];
    const float* b_ff1 = (const float*)d_in[17];
    const float* w_ff2 = (const float*)d_in[18];
    const float* b_ff2 = (const float*)d_in[19];
    const float* w_pw1 = (const float*)d_in[20];
    const float* b_pw1 = (const float*)d_in[21];
    const float* w_dw  = (const float*)d_in[22];
    const float* b_dw  = (const float*)d_in[23];
    const float* w_pw2 = (const float*)d_in[24];
    const float* b_pw2 = (const float*)d_in[25];
    const float* neps  = (const float*)d_in[26];

    float* out_x = (float*)d_out;                       // 4096*512
    float* out_s = (float*)d_out + 2097152;             // 4*1024*1024*8

    // ---- workspace layout (float units) ----
    float* ws = (float*)d_ws;
    float* xbuf = ws;                               // 2,097,152
    float* U    = xbuf + 2097152;                   // 6,291,456 (hb16 | hbuf+gbuf)
    float* sbbf = U + 6291456;                      // 1,048,576 (src bf16 | dbufb)
    float* xb16f= sbbf + 1048576;                   // 1,048,576
    float* qkvb = xb16f + 1048576;                  // 3,145,728 (later p2)
    float* qu   = qkvb + 3145728;                   // 1,048,576 (later ctxb)
    float* qv   = qu + 1048576;                     // 1,048,576
    float* kbuf = qv + 1048576;                     // 1,048,576
    float* vbuf = kbuf + 1048576;                   // 1,048,576
    float* pbuf = vbuf + 1048576;                   // 524,288
    float* wbf  = pbuf + 524288;                    // 524,288 (weight bf16 staging)
    float* posbf= wbf + 524288;                     // 524,288 (pos bf16, 2048x512)
    float* totf = posbf + 524288;                   // 16,777,216 (bf16 tot)

    unsigned short* hb16  = (unsigned short*)U;           // 8,388,608 elems
    float*          hbuf  = U;                            // pw1 out (4096x1024)
    float*          gbuf  = U + 4194304;                  // GLU out (4096x512)
    unsigned short* sbb   = (unsigned short*)sbbf;        // src bf16
    unsigned short* dbufb = (unsigned short*)sbbf;        // dwconv out bf16
    unsigned short* xb16  = (unsigned short*)xb16f;       // x bf16
    unsigned short* ctxb  = (unsigned short*)qu;          // ctx bf16
    unsigned short* wb    = (unsigned short*)wbf;         // weight staging
    unsigned short* posb  = (unsigned short*)posbf;       // pos bf16 padded
    unsigned short* totb  = (unsigned short*)totf;        // scores/attn bf16
    float*          p2    = qkvb;

    dim3 blk(256);
    const int M = 4096;

    // --- macaron FFN ---
    cast_bf16_kernel<<<2048, blk, 0, stream>>>((const float4*)src, (ushort4*)sbb, 524288);
    cast_bf16_kernel<<<1024, blk, 0, stream>>>((const float4*)w_ff1m, (ushort4*)wb, 262144);
    mfma_gemm<1,0,0,1><<<dim3(16, 32), blk, 0, stream>>>(
        sbb, wb, b_ff1m, nullptr, nullptr, hb16, M, 2048, 512);
    cast_bf16_kernel<<<1024, blk, 0, stream>>>((const float4*)w_ff2m, (ushort4*)wb, 262144);
    mfma_gemm<0,1,1,1><<<dim3(4, 32), blk, 0, stream>>>(
        hb16, wb, b_ff2m, src, xbuf, xb16, M, 512, 2048);

    // --- attention ---
    cast_bf16_kernel<<<384, blk, 0, stream>>>((const float4*)w_in, (ushort4*)wb, 98304);
    mfma_gemm<0,0,1,0><<<dim3(6, 32), blk, 0, stream>>>(
        xb16, wb, b_in, nullptr, qkvb, nullptr, M, 768, 512);
    split_kernel<<<4096, blk, 0, stream>>>(qkvb, pbu, pbv, qu, qv, kbuf, vbuf);
    // pos projection via MFMA (M=2047 padded to 2048)
    cast_bf16_kernel<<<1024, blk, 0, stream>>>((const float4*)pos, (ushort4*)posb, 262016);
    cast_bf16_kernel<<<128, blk, 0, stream>>>((const float4*)w_pos, (ushort4*)wb, 32768);
    mfma_gemm<0,0,1,0><<<dim3(2, 16), blk, 0, stream>>>(
        posb, wb, nullptr, nullptr, pbuf, nullptr, 2047, 256, 512);
    repack_p_kernel<<<2047, blk, 0, stream>>>(pbuf, p2);
    scores_kernel<<<dim3(16, 16, 32), blk, 0, stream>>>(qu, qv, kbuf, p2, totb);
    attn_finish_kernel<<<4096, blk, 0, stream>>>(totb, as_, prin, prout, out_s);
    ctx_kernel<<<dim3(16, 32), blk, 0, stream>>>(totb, vbuf, ctxb);
    cast_bf16_kernel<<<128, blk, 0, stream>>>((const float4*)w_out, (ushort4*)wb, 32768);
    mfma_gemm<0,1,1,1><<<dim3(4, 32), blk, 0, stream>>>(
        ctxb, wb, b_out, xbuf, xbuf, xb16, M, 512, 256);

    // --- conv module ---
    cast_bf16_kernel<<<512, blk, 0, stream>>>((const float4*)w_pw1, (ushort4*)wb, 131072);
    mfma_gemm<0,0,1,0><<<dim3(8, 32), blk, 0, stream>>>(
        xb16, wb, b_pw1, nullptr, hbuf, nullptr, M, 1024, 512);
    glu_kernel<<<8192, blk, 0, stream>>>(hbuf, gbuf);
    dwconv_kernel<<<8192, blk, 0, stream>>>(gbuf, w_dw, b_dw, dbufb);
    cast_bf16_kernel<<<256, blk, 0, stream>>>((const float4*)w_pw2, (ushort4*)wb, 65536);
    mfma_gemm<0,1,1,1><<<dim3(4, 32), blk, 0, stream>>>(
        dbufb, wb, b_pw2, xbuf, xbuf, xb16, M, 512, 512);

    // --- final FFN + BasicNorm ---
    cast_bf16_kernel<<<1024, blk, 0, stream>>>((const float4*)w_ff1, (ushort4*)wb, 262144);
    mfma_gemm<1,0,0,1><<<dim3(16, 32), blk, 0, stream>>>(
        xb16, wb, b_ff1, nullptr, nullptr, hb16, M, 2048, 512);
    cast_bf16_kernel<<<1024, blk, 0, stream>>>((const float4*)w_ff2, (ushort4*)wb, 262144);
    mfma_gemm<0,1,1,0><<<dim3(4, 32), blk, 0, stream>>>(
        hb16, wb, b_ff2, xbuf, xbuf, nullptr, M, 512, 2048);
    norm_kernel<<<4096, blk, 0, stream>>>(xbuf, neps, out_x);
}

// Round 6
// 708.412 us; speedup vs baseline: 1.4774x; 1.0723x over previous
//
#include <hip/hip_runtime.h>

#define DEV_INLINE __device__ __forceinline__

typedef short bf16x8 __attribute__((ext_vector_type(8)));
typedef float f32x4 __attribute__((ext_vector_type(4)));
typedef unsigned short u16x8 __attribute__((ext_vector_type(8)));

DEV_INLINE float sigmoidf_(float x) { return 1.f / (1.f + __expf(-x)); }
DEV_INLINE float dot4_(float4 a, float4 b) {
    return a.x * b.x + a.y * b.y + a.z * b.z + a.w * b.w;
}
DEV_INLINE unsigned short f2bf(float x) {
    unsigned int u = __float_as_uint(x);
    unsigned int r = (u + 0x7FFFu + ((u >> 16) & 1u)) >> 16;
    return (unsigned short)r;
}
DEV_INLINE float bf2f(unsigned short u) {
    return __uint_as_float(((unsigned int)u) << 16);
}

// ---------------------------------------------------------------------------
// mega-cast: all fp32->bf16 casts in one launch
// ---------------------------------------------------------------------------
struct CastJobs {
    const float4* src[11];
    ushort4* dst[11];
    int end[11];          // cumulative end, float4 units
};

__global__ __launch_bounds__(256) void cast_all_kernel(CastJobs jobs, int total4)
{
    int gi = blockIdx.x * 256 + threadIdx.x;
    if (gi >= total4) return;
    int s = 0, base = 0;
    while (gi >= jobs.end[s]) { base = jobs.end[s]; s++; }
    int li = gi - base;
    float4 v = jobs.src[s][li];
    ushort4 o = {f2bf(v.x), f2bf(v.y), f2bf(v.z), f2bf(v.w)};
    jobs.dst[s][li] = o;
}

// ---------------------------------------------------------------------------
// bf16 MFMA GEMM (m97 structure): C[M,N] = act(A[M,K] @ B[N,K]^T + bias)(+res)
// ---------------------------------------------------------------------------
template<int ACT, int RES, int WF32, int WBF>
__global__ __launch_bounds__(256) void mfma_gemm(
    const unsigned short* __restrict__ A, const unsigned short* __restrict__ B,
    const float* __restrict__ bias, const float* __restrict__ res,
    float* __restrict__ C, unsigned short* __restrict__ Cb, int M, int N, int K)
{
    __shared__ __align__(16) unsigned short As[128 * 32];
    __shared__ __align__(16) unsigned short Bs[128 * 32];

    const int t = threadIdx.x;
    const int lane = t & 63, wave = t >> 6;
    const int wr = wave >> 1, wc = wave & 1;
    const int lr = lane & 15, lk = lane >> 4;
    const int m0 = blockIdx.y * 128, n0 = blockIdx.x * 128;

    f32x4 acc[4][4] = {};

    for (int k0 = 0; k0 < K; k0 += 32) {
#pragma unroll
        for (int c = 0; c < 2; c++) {
            int bo = t * 16 + c * 4096;
            int row = bo >> 6;
            int col = (bo & 63) >> 1;
            __builtin_amdgcn_global_load_lds(
                (const __attribute__((address_space(1))) void*)(A + (size_t)(m0 + row) * K + k0 + col),
                (__attribute__((address_space(3))) void*)(As + (bo >> 1)), 16, 0, 0);
            __builtin_amdgcn_global_load_lds(
                (const __attribute__((address_space(1))) void*)(B + (size_t)(n0 + row) * K + k0 + col),
                (__attribute__((address_space(3))) void*)(Bs + (bo >> 1)), 16, 0, 0);
        }
        __syncthreads();

        bf16x8 af[4], bfr[4];
#pragma unroll
        for (int mi = 0; mi < 4; mi++)
            af[mi] = *(const bf16x8*)(As + (wr * 64 + mi * 16 + lr) * 32 + lk * 8);
#pragma unroll
        for (int nj = 0; nj < 4; nj++)
            bfr[nj] = *(const bf16x8*)(Bs + (wc * 64 + nj * 16 + lr) * 32 + lk * 8);
#pragma unroll
        for (int mi = 0; mi < 4; mi++)
#pragma unroll
            for (int nj = 0; nj < 4; nj++)
                acc[mi][nj] = __builtin_amdgcn_mfma_f32_16x16x32_bf16(
                    af[mi], bfr[nj], acc[mi][nj], 0, 0, 0);
        __syncthreads();
    }

#pragma unroll
    for (int nj = 0; nj < 4; nj++) {
        int col = n0 + wc * 64 + nj * 16 + lr;
        float bv = bias ? bias[col] : 0.f;
#pragma unroll
        for (int mi = 0; mi < 4; mi++) {
            int row = m0 + wr * 64 + mi * 16 + lk * 4;
#pragma unroll
            for (int j = 0; j < 4; j++) {
                int r = row + j;
                if (r >= M) continue;
                float v = acc[mi][nj][j] + bv;
                if (ACT) v = v * sigmoidf_(v - 1.f);
                size_t off = (size_t)r * N + col;
                if (RES) v += res[off];
                if (WF32) C[off] = v;
                if (WBF) Cb[off] = f2bf(v);
            }
        }
    }
}

// ---------------------------------------------------------------------------
// Split qkv (L,N,768) into qu/qv/k/v in (N,H,L,d) layout
// ---------------------------------------------------------------------------
__global__ __launch_bounds__(256) void split_kernel(
    const float* __restrict__ qkv,
    const float* __restrict__ pbu, const float* __restrict__ pbv,
    float* __restrict__ qu, float* __restrict__ qv,
    float* __restrict__ kb, float* __restrict__ vb)
{
    int idx = blockIdx.x * 256 + threadIdx.x;
    int dd = idx & 31;
    int l  = (idx >> 5) & 1023;
    int h  = (idx >> 15) & 7;
    int n  = idx >> 18;
    size_t base = ((size_t)l * 4 + n) * 768 + h * 32 + dd;
    float q = qkv[base];
    qu[idx] = q + pbu[h * 32 + dd];
    qv[idx] = q + pbv[h * 32 + dd];
    kb[idx] = qkv[base + 256];
    vb[idx] = qkv[base + 512];
}

// ---------------------------------------------------------------------------
// Repack p (m,h,d) -> p2 (h,m,d)
// ---------------------------------------------------------------------------
__global__ __launch_bounds__(256) void repack_p_kernel(
    const float* __restrict__ pb, float* __restrict__ p2)
{
    int idx = blockIdx.x * 256 + threadIdx.x;
    if (idx >= 2047 * 256) return;
    int dd = idx & 31;
    int h  = (idx >> 5) & 7;
    int m  = idx >> 8;
    p2[((size_t)h * 2047 + m) * 32 + dd] = pb[idx];
}

// ---------------------------------------------------------------------------
// scores_kernel v2 (conflict-free): totb[n,h,i,j] = bf16((ac + bd) * scale)
// Per-thread tile: rows il = ty+16*ii, cols jl = tx+16*jj (strided).
// K/P in row-major [row][9] float4 padded LDS (2-way max on reads).
// Output staged through LDS for contiguous global stores.
// ---------------------------------------------------------------------------
__global__ __launch_bounds__(256) void scores_kernel(
    const float* __restrict__ qu, const float* __restrict__ qv,
    const float* __restrict__ kb, const float* __restrict__ p2,
    unsigned short* __restrict__ totb)
{
    __shared__ __align__(16) float4 Qu4[8][64];        // [dg][i]
    __shared__ __align__(16) float4 Qv4[8][64];
    __shared__ __align__(16) float4 K4p[64 * 9];       // [j*9+dg]
    __shared__ __align__(16) float4 P4p[127 * 9 + 1];  // [m*9+dg]
    __shared__ __align__(16) unsigned short staged[64][72];

    const int t = threadIdx.x;
    const int tx = t & 15, ty = t >> 4;
    const int j0 = blockIdx.x * 64, i0 = blockIdx.y * 64;
    const int nh = blockIdx.z;
    const int h = nh & 7;
    const int m_base = 960 - i0 + j0;   // >= 0 always

    const float4* qug = (const float4*)(qu + ((size_t)nh * 1024 + i0) * 32);
    const float4* qvg = (const float4*)(qv + ((size_t)nh * 1024 + i0) * 32);
    const float4* kg  = (const float4*)(kb + ((size_t)nh * 1024 + j0) * 32);
    const float4* pg  = (const float4*)(p2 + ((size_t)h * 2047 + m_base) * 32);

#pragma unroll
    for (int c = 0; c < 2; c++) {
        int fi = t + 256 * c;
        int r = fi >> 3, dg = fi & 7;
        Qu4[dg][r] = qug[fi];
        Qv4[dg][r] = qvg[fi];
        K4p[r * 9 + dg] = kg[fi];
    }
#pragma unroll
    for (int c = 0; c < 4; c++) {
        int fi = t + 256 * c;
        if (fi < 127 * 8) {
            int r = fi >> 3, dg = fi & 7;
            P4p[r * 9 + dg] = pg[fi];
        }
    }
    __syncthreads();

    float acc[4][4] = {};
    const int pbase = 63 + tx - ty;     // p_[s] row = pbase + 16*(s-3), in [0,126]

#pragma unroll
    for (int dg = 0; dg < 8; dg++) {
        float4 qu_[4], qv_[4], k_[4], p_[7];
#pragma unroll
        for (int ii = 0; ii < 4; ii++) {
            qu_[ii] = Qu4[dg][ty + 16 * ii];
            qv_[ii] = Qv4[dg][ty + 16 * ii];
        }
#pragma unroll
        for (int jj = 0; jj < 4; jj++)
            k_[jj] = K4p[(tx + 16 * jj) * 9 + dg];
#pragma unroll
        for (int s = 0; s < 7; s++)
            p_[s] = P4p[(pbase + 16 * (s - 3)) * 9 + dg];
#pragma unroll
        for (int ii = 0; ii < 4; ii++)
#pragma unroll
            for (int jj = 0; jj < 4; jj++)
                acc[ii][jj] += dot4_(qu_[ii], k_[jj]) + dot4_(qv_[ii], p_[jj - ii + 3]);
    }

    const float scale = 0.17677669529663687f;
#pragma unroll
    for (int ii = 0; ii < 4; ii++)
#pragma unroll
        for (int jj = 0; jj < 4; jj++)
            staged[ty + 16 * ii][tx + 16 * jj] = f2bf(acc[ii][jj] * scale);
    __syncthreads();

    unsigned short* o = totb + ((size_t)nh * 1024 + i0) * 1024 + j0;
    int r = t >> 2, q = t & 3;
    u16x8 v0 = *(const u16x8*)&staged[r][q * 16];
    u16x8 v1 = *(const u16x8*)&staged[r][q * 16 + 8];
    *(u16x8*)(o + (size_t)r * 1024 + q * 16) = v0;
    *(u16x8*)(o + (size_t)r * 1024 + q * 16 + 8) = v1;
}

// ---------------------------------------------------------------------------
// attn_finish_kernel (register-resident)
// ---------------------------------------------------------------------------
__global__ __launch_bounds__(256) void attn_finish_kernel(
    unsigned short* __restrict__ totb, const float* __restrict__ as_,
    const float* __restrict__ proj_in, const float* __restrict__ proj_out,
    float* __restrict__ out_s)
{
    __shared__ float pin_s[64], po_s[64];
    __shared__ float redbuf[4][8];

    const int t = threadIdx.x;
    const int n = blockIdx.x >> 10;
    const int i = blockIdx.x & 1023;
    const int j0 = t * 4;
    const int wave = t >> 6, lane = t & 63;

    if (t < 64) { pin_s[t] = proj_in[t]; po_s[t] = proj_out[t]; }
    __syncthreads();

    float th[8][4];
#pragma unroll
    for (int h = 0; h < 8; h++) {
        ushort4 u = *(const ushort4*)(totb + ((size_t)(n * 8 + h) * 1024 + i) * 1024 + j0);
        th[h][0] = bf2f(u.x); th[h][1] = bf2f(u.y);
        th[h][2] = bf2f(u.z); th[h][3] = bf2f(u.w);
    }

    const float4* as4 = (const float4*)(as_ + (((size_t)n * 1024 + i) * 1024 + j0) * 8);
    float4* os4 = (float4*)(out_s + (((size_t)n * 1024 + i) * 1024 + j0) * 8);

#pragma unroll
    for (int jj = 0; jj < 4; jj++) {
        float4 alo = as4[jj * 2], ahi = as4[jj * 2 + 1];
        float ag[8] = {alo.x, alo.y, alo.z, alo.w, ahi.x, ahi.y, ahi.z, ahi.w};
#pragma unroll
        for (int h = 0; h < 8; h++) {
            float si = 0.f;
#pragma unroll
            for (int g = 0; g < 8; g++) si += ag[g] * pin_s[g * 8 + h];
            th[h][jj] += si;
        }
        float so[8];
#pragma unroll
        for (int g = 0; g < 8; g++) {
            float s = ag[g];
#pragma unroll
            for (int h = 0; h < 8; h++) s += th[h][jj] * po_s[h * 8 + g];
            so[g] = s;
        }
        float4 o0 = {so[0], so[1], so[2], so[3]};
        float4 o1 = {so[4], so[5], so[6], so[7]};
        os4[jj * 2] = o0;
        os4[jj * 2 + 1] = o1;
    }

    float mx[8];
#pragma unroll
    for (int h = 0; h < 8; h++)
        mx[h] = fmaxf(fmaxf(th[h][0], th[h][1]), fmaxf(th[h][2], th[h][3]));
#pragma unroll
    for (int d = 1; d < 64; d <<= 1)
#pragma unroll
        for (int h = 0; h < 8; h++) mx[h] = fmaxf(mx[h], __shfl_xor(mx[h], d));
    if (lane == 0)
#pragma unroll
        for (int h = 0; h < 8; h++) redbuf[wave][h] = mx[h];
    __syncthreads();
#pragma unroll
    for (int h = 0; h < 8; h++)
        mx[h] = fmaxf(fmaxf(redbuf[0][h], redbuf[1][h]),
                      fmaxf(redbuf[2][h], redbuf[3][h]));
    __syncthreads();

    float sm[8];
#pragma unroll
    for (int h = 0; h < 8; h++) {
        float s = 0.f;
#pragma unroll
        for (int jj = 0; jj < 4; jj++) {
            th[h][jj] = __expf(th[h][jj] - mx[h]);
            s += th[h][jj];
        }
        sm[h] = s;
    }
#pragma unroll
    for (int d = 1; d < 64; d <<= 1)
#pragma unroll
        for (int h = 0; h < 8; h++) sm[h] += __shfl_xor(sm[h], d);
    if (lane == 0)
#pragma unroll
        for (int h = 0; h < 8; h++) redbuf[wave][h] = sm[h];
    __syncthreads();

#pragma unroll
    for (int h = 0; h < 8; h++) {
        float rs = 1.f / (redbuf[0][h] + redbuf[1][h] + redbuf[2][h] + redbuf[3][h]);
        ushort4 o = {f2bf(th[h][0] * rs), f2bf(th[h][1] * rs),
                     f2bf(th[h][2] * rs), f2bf(th[h][3] * rs)};
        *(ushort4*)(totb + ((size_t)(n * 8 + h) * 1024 + i) * 1024 + j0) = o;
    }
}

// ---------------------------------------------------------------------------
// ctx_kernel: ctx[i, n, h*32+d] = sum_j attn_bf16[i,j]*v[j,d]  (bf16 output)
// ---------------------------------------------------------------------------
__global__ __launch_bounds__(256) void ctx_kernel(
    const unsigned short* __restrict__ attnb, const float* __restrict__ vb,
    unsigned short* __restrict__ ctx_b)
{
    __shared__ float At[64][128];
    __shared__ float Vs[128][32];

    const int t = threadIdx.x;
    const int i0 = blockIdx.x * 64;
    const int nh = blockIdx.y;
    const int n = nh >> 3, h = nh & 7;
    const int tx = t & 31, ty = t >> 5;

    float acc[8] = {};
    const unsigned short* abase = attnb + ((size_t)nh * 1024 + i0) * 1024;
    const float* vbase = vb + (size_t)nh * 1024 * 32;

    for (int jc = 0; jc < 8; jc++) {
#pragma unroll
        for (int c = 0; c < 8; c++) {
            int fi = t + 256 * c;
            int r = fi >> 5, c4 = fi & 31;
            ushort4 u = ((const ushort4*)(abase + (size_t)r * 1024 + jc * 128))[c4];
            float4 f = {bf2f(u.x), bf2f(u.y), bf2f(u.z), bf2f(u.w)};
            ((float4*)At[r])[c4] = f;
        }
#pragma unroll
        for (int c = 0; c < 4; c++) {
            int fi = t + 256 * c;
            int r = fi >> 3, dg = fi & 7;
            ((float4*)Vs[r])[dg] =
                ((const float4*)(vbase + (size_t)(jc * 128 + r) * 32))[dg];
        }
        __syncthreads();
#pragma unroll
        for (int jj = 0; jj < 32; jj++) {
            float v0 = Vs[jj * 4 + 0][tx];
            float v1 = Vs[jj * 4 + 1][tx];
            float v2 = Vs[jj * 4 + 2][tx];
            float v3 = Vs[jj * 4 + 3][tx];
#pragma unroll
            for (int ii = 0; ii < 8; ii++) {
                float4 av = ((float4*)At[ty * 8 + ii])[jj];
                acc[ii] += av.x * v0 + av.y * v1 + av.z * v2 + av.w * v3;
            }
        }
        __syncthreads();
    }

#pragma unroll
    for (int ii = 0; ii < 8; ii++) {
        int i = i0 + ty * 8 + ii;
        ctx_b[((size_t)i * 4 + n) * 256 + h * 32 + tx] = f2bf(acc[ii]);
    }
}

// ---------------------------------------------------------------------------
// GLU (vectorized, bf16 out): g[r,c] = a * sigmoid(b)
// ---------------------------------------------------------------------------
__global__ __launch_bounds__(256) void glu_kernel(
    const float* __restrict__ h1, unsigned short* __restrict__ g)
{
    int idx4 = blockIdx.x * 256 + threadIdx.x;     // over 4096*128
    int r = idx4 >> 7, c4 = idx4 & 127;
    const float4* row = (const float4*)(h1 + (size_t)r * 1024);
    float4 a = row[c4];
    float4 b = row[128 + c4];
    ushort4 o = {f2bf(a.x * sigmoidf_(b.x)), f2bf(a.y * sigmoidf_(b.y)),
                 f2bf(a.z * sigmoidf_(b.z)), f2bf(a.w * sigmoidf_(b.w))};
    ((ushort4*)g)[idx4] = o;
}

// ---------------------------------------------------------------------------
// depthwise conv (K=31, pad 15) + bias + DoubleSwish; bf16 in -> bf16 out
// ---------------------------------------------------------------------------
__global__ __launch_bounds__(256) void dwconv_kernel(
    const unsigned short* __restrict__ g, const float* __restrict__ w_dw,
    const float* __restrict__ b_dw, unsigned short* __restrict__ out)
{
    int idx = blockIdx.x * 256 + threadIdx.x;
    int c = idx & 511;
    int r = idx >> 9;
    int nn = r & 3, l = r >> 2;
    float acc = b_dw[c];
#pragma unroll
    for (int kk = 0; kk < 31; kk++) {
        int l2 = l + kk - 15;
        if (l2 >= 0 && l2 < 1024)
            acc += bf2f(g[(((size_t)l2 * 4 + nn) << 9) + c]) * w_dw[c * 31 + kk];
    }
    out[idx] = f2bf(acc * sigmoidf_(acc - 1.f));
}

// ---------------------------------------------------------------------------
// BasicNorm
// ---------------------------------------------------------------------------
__global__ __launch_bounds__(256) void norm_kernel(
    const float* __restrict__ x, const float* __restrict__ eps_p,
    float* __restrict__ out)
{
    int r = blockIdx.x, t = threadIdx.x;
    float a = x[(size_t)r * 512 + t];
    float b = x[(size_t)r * 512 + 256 + t];
    float ss = a * a + b * b;
#pragma unroll
    for (int d = 1; d < 64; d <<= 1) ss += __shfl_xor(ss, d);
    __shared__ float red[4];
    if ((t & 63) == 0) red[t >> 6] = ss;
    __syncthreads();
    float tot = red[0] + red[1] + red[2] + red[3];
    float scale = rsqrtf(tot * (1.f / 512.f) + __expf(eps_p[0]));
    out[(size_t)r * 512 + t] = a * scale;
    out[(size_t)r * 512 + 256 + t] = b * scale;
}

// ---------------------------------------------------------------------------
extern "C" void kernel_launch(void* const* d_in, const int* in_sizes, int n_in,
                              void* d_out, int out_size, void* d_ws, size_t ws_size,
                              hipStream_t stream)
{
    const float* src   = (const float*)d_in[0];
    const float* pos   = (const float*)d_in[1];
    const float* as_   = (const float*)d_in[2];
    const float* w_in  = (const float*)d_in[3];
    const float* b_in  = (const float*)d_in[4];
    const float* w_pos = (const float*)d_in[5];
    const float* pbu   = (const float*)d_in[6];
    const float* pbv   = (const float*)d_in[7];
    const float* prin  = (const float*)d_in[8];
    const float* prout = (const float*)d_in[9];
    const float* w_out = (const float*)d_in[10];
    const float* b_out = (const float*)d_in[11];
    const float* w_ff1m = (const float*)d_in[12];
    const float* b_ff1m = (const float*)d_in[13];
    const float* w_ff2m = (const float*)d_in[14];
    const float* b_ff2m = (const float*)d_in[15];
    const float* w_ff1 = (const float*)d_in[16];
    const float* b_ff1 = (const float*)d_in[17];
    const float* w_ff2 = (const float*)d_in[18];
    const float* b_ff2 = (const float*)d_in[19];
    const float* w_pw1 = (const float*)d_in[20];
    const float* b_pw1 = (const float*)d_in[21];
    const float* w_dw  = (const float*)d_in[22];
    const float* b_dw  = (const float*)d_in[23];
    const float* w_pw2 = (const float*)d_in[24];
    const float* b_pw2 = (const float*)d_in[25];
    const float* neps  = (const float*)d_in[26];

    float* out_x = (float*)d_out;
    float* out_s = (float*)d_out + 2097152;

    // ---- workspace layout (float units) ----
    float* ws = (float*)d_ws;
    float* xbuf = ws;                               // 2,097,152
    float* U    = xbuf + 2097152;                   // 6,291,456
    float* sbbf = U + 6291456;                      // 1,048,576
    float* xb16f= sbbf + 1048576;                   // 1,048,576
    float* qkvb = xb16f + 1048576;                  // 3,145,728 (later p2)
    float* qu   = qkvb + 3145728;                   // 1,048,576 (later ctxb)
    float* qv   = qu + 1048576;                     // 1,048,576
    float* kbuf = qv + 1048576;                     // 1,048,576
    float* vbuf = kbuf + 1048576;                   // 1,048,576
    float* pbuf = vbuf + 1048576;                   // 524,288
    float* posbf= pbuf + 524288;                    // 524,288
    float* totf = posbf + 524288;                   // 16,777,216
    float* Wreg = totf + 16777216;                  // weights bf16 region

    unsigned short* hb16  = (unsigned short*)U;
    float*          hbuf  = U;                            // pw1 out fp32
    unsigned short* gbuf  = (unsigned short*)(U + 4194304);  // GLU out bf16
    unsigned short* sbb   = (unsigned short*)sbbf;
    unsigned short* dbufb = (unsigned short*)sbbf;
    unsigned short* xb16  = (unsigned short*)xb16f;
    unsigned short* ctxb  = (unsigned short*)qu;
    unsigned short* posb  = (unsigned short*)posbf;
    unsigned short* totb  = (unsigned short*)totf;
    float*          p2    = qkvb;

    // per-weight bf16 buffers (sizes in floats = elems/2)
    float* wp = Wreg;
    unsigned short* wff1m_b = (unsigned short*)wp; wp += 524288;
    unsigned short* wff2m_b = (unsigned short*)wp; wp += 524288;
    unsigned short* win_b   = (unsigned short*)wp; wp += 196608;
    unsigned short* wpos_b  = (unsigned short*)wp; wp += 65536;
    unsigned short* wout_b  = (unsigned short*)wp; wp += 65536;
    unsigned short* wpw1_b  = (unsigned short*)wp; wp += 262144;
    unsigned short* wpw2_b  = (unsigned short*)wp; wp += 131072;
    unsigned short* wff1_b  = (unsigned short*)wp; wp += 524288;
    unsigned short* wff2_b  = (unsigned short*)wp; wp += 524288;

    dim3 blk(256);
    const int M = 4096;

    // --- one mega-cast for src, pos, and all weights ---
    {
        CastJobs jobs;
        const float* srcs[11] = {src, pos, w_ff1m, w_ff2m, w_in, w_pos,
                                 w_out, w_pw1, w_pw2, w_ff1, w_ff2};
        unsigned short* dsts[11] = {sbb, posb, wff1m_b, wff2m_b, win_b, wpos_b,
                                    wout_b, wpw1_b, wpw2_b, wff1_b, wff2_b};
        int n4s[11] = {524288, 262016, 262144, 262144, 98304, 32768,
                       32768, 131072, 65536, 262144, 262144};
        int cum = 0;
        for (int s = 0; s < 11; s++) {
            jobs.src[s] = (const float4*)srcs[s];
            jobs.dst[s] = (ushort4*)dsts[s];
            cum += n4s[s];
            jobs.end[s] = cum;
        }
        cast_all_kernel<<<(cum + 255) / 256, blk, 0, stream>>>(jobs, cum);
    }

    // --- macaron FFN ---
    mfma_gemm<1,0,0,1><<<dim3(16, 32), blk, 0, stream>>>(
        sbb, wff1m_b, b_ff1m, nullptr, nullptr, hb16, M, 2048, 512);
    mfma_gemm<0,1,1,1><<<dim3(4, 32), blk, 0, stream>>>(
        hb16, wff2m_b, b_ff2m, src, xbuf, xb16, M, 512, 2048);

    // --- attention ---
    mfma_gemm<0,0,1,0><<<dim3(6, 32), blk, 0, stream>>>(
        xb16, win_b, b_in, nullptr, qkvb, nullptr, M, 768, 512);
    split_kernel<<<4096, blk, 0, stream>>>(qkvb, pbu, pbv, qu, qv, kbuf, vbuf);
    mfma_gemm<0,0,1,0><<<dim3(2, 16), blk, 0, stream>>>(
        posb, wpos_b, nullptr, nullptr, pbuf, nullptr, 2047, 256, 512);
    repack_p_kernel<<<2047, blk, 0, stream>>>(pbuf, p2);
    scores_kernel<<<dim3(16, 16, 32), blk, 0, stream>>>(qu, qv, kbuf, p2, totb);
    attn_finish_kernel<<<4096, blk, 0, stream>>>(totb, as_, prin, prout, out_s);
    ctx_kernel<<<dim3(16, 32), blk, 0, stream>>>(totb, vbuf, ctxb);
    mfma_gemm<0,1,1,1><<<dim3(4, 32), blk, 0, stream>>>(
        ctxb, wout_b, b_out, xbuf, xbuf, xb16, M, 512, 256);

    // --- conv module ---
    mfma_gemm<0,0,1,0><<<dim3(8, 32), blk, 0, stream>>>(
        xb16, wpw1_b, b_pw1, nullptr, hbuf, nullptr, M, 1024, 512);
    glu_kernel<<<2048, blk, 0, stream>>>(hbuf, gbuf);
    dwconv_kernel<<<8192, blk, 0, stream>>>(gbuf, w_dw, b_dw, dbufb);
    mfma_gemm<0,1,1,1><<<dim3(4, 32), blk, 0, stream>>>(
        dbufb, wpw2_b, b_pw2, xbuf, xbuf, xb16, M, 512, 512);

    // --- final FFN + BasicNorm ---
    mfma_gemm<1,0,0,1><<<dim3(16, 32), blk, 0, stream>>>(
        xb16, wff1_b, b_ff1, nullptr, nullptr, hb16, M, 2048, 512);
    mfma_gemm<0,1,1,0><<<dim3(4, 32), blk, 0, stream>>>(
        hb16, wff2_b, b_ff2, xbuf, xbuf, nullptr, M, 512, 2048);
    norm_kernel<<<4096, blk, 0, stream>>>(xbuf, neps, out_x);
}